// Round 10
// baseline (7428.100 us; speedup 1.0000x reference)
//
#include <hip/hip_runtime.h>
#include <hip/hip_bf16.h>

// Problem constants
#define BB   128
#define SS   512
#define IND  512
#define HID  1024
#define NBLK 256     // 4 row-quarters (mi) x 64 column-groups (jg)
#define GRPBLK 64    // blocks per mi-group (independent sub-GRU)
#define NSTRIPE 8    // stripes per group (one 64B LLC line each)
#define NTHR 384     // 6 waves = 2 row-halves x 3 gates

#define WHH_LD (HID + 8)   // LDS row pad
#define WIH_LD (IND + 8)

typedef __attribute__((ext_vector_type(8))) short s8v;   // 8 x bf16
typedef __attribute__((ext_vector_type(4))) float f4v;   // MFMA accumulator
typedef unsigned long long u64;
typedef unsigned int u32;

__device__ __forceinline__ short f2bf(float f) {
    union { float f; u32 u; } v; v.f = f;
    u32 u = v.u + 0x7FFFu + ((v.u >> 16) & 1u);          // RNE
    return (short)(u >> 16);
}

// h ping-pong layout (bf16): as R8 (PROVEN).
//   bufA (ws): [wg=8][kk=32][kg=4][row 16][8 shorts]
//   bufB (out tail): group mi slice at mi*131072 + (wg&1)*32768 + rest
// Waves: wave = g*2 + rw;  g in {0=r, 1=z, 2=n}, rw = row half.
// Each gate-wave runs R8's EXACT accumulation chain for its gate ->
// h evolution bit-identical to R8. z/n waves pass partials via LDS;
// r-waves run R8's epilogue verbatim and store h/out.

__global__ void __launch_bounds__(NTHR, 1)
gru_persistent(const float* __restrict__ X,     // [B,S,IND]
               const float* __restrict__ Wih,   // [3H, IND]
               const float* __restrict__ Whh,   // [3H, HID]
               const float* __restrict__ bih,   // [3H]
               const float* __restrict__ bhh,   // [3H]
               float* __restrict__ out,         // [B,S,H] ++ [B,H]
               short* __restrict__ bufA,        // ws scratch (even t)
               short* __restrict__ bufB,        // d_out tail region (odd t)
               u64*   __restrict__ ctr)         // 4 groups x 8 stripes, 64B apart
{
    __shared__ __align__(16) short whh_lds[48 * WHH_LD];   // 99072 B
    __shared__ __align__(16) short wih_lds[48 * WIH_LD];   // 49920 B
    __shared__ __align__(16) f4v  red_lds[3][2][64];       //  6144 B  (z, in, hn)

    const int tid  = threadIdx.x;
    const int wave = tid >> 6;      // 0..5
    const int lane = tid & 63;
    const int blk  = blockIdx.x;
    const int mi   = blk >> 6;      // 0..3 row quarter == barrier group
    const int jg   = blk & 63;      // column group

    const int g  = wave >> 1;       // gate: 0=r, 1=z, 2=n
    const int rw = wave & 1;        // row half

    // ---- stage weight slices to LDS as bf16 (once) ----
    for (int idx = tid; idx < 48 * (HID / 4); idx += NTHR) {
        int s = idx / (HID / 4), k4 = idx % (HID / 4);
        int grow = (s >> 4) * HID + jg * 16 + (s & 15);
        float4 v = *(const float4*)(Whh + (size_t)grow * HID + k4 * 4);
        short* d = &whh_lds[s * WHH_LD + k4 * 4];
        d[0] = f2bf(v.x); d[1] = f2bf(v.y); d[2] = f2bf(v.z); d[3] = f2bf(v.w);
    }
    for (int idx = tid; idx < 48 * (IND / 4); idx += NTHR) {
        int s = idx / (IND / 4), k4 = idx % (IND / 4);
        int grow = (s >> 4) * HID + jg * 16 + (s & 15);
        float4 v = *(const float4*)(Wih + (size_t)grow * IND + k4 * 4);
        short* d = &wih_lds[s * WIH_LD + k4 * 4];
        d[0] = f2bf(v.x); d[1] = f2bf(v.y); d[2] = f2bf(v.z); d[3] = f2bf(v.w);
    }

    const int n  = lane & 15;
    const int kg = lane >> 4;
    const int j  = jg * 16 + n;
    const float bir = bih[j], biz = bih[HID + j], bin_ = bih[2 * HID + j];
    const float bhr = bhh[j], bhz = bhh[HID + j], bhn  = bhh[2 * HID + j];

    const int rowbase = mi * 32 + rw * 16;
    const int wg      = mi * 2 + rw;            // row-group = rowbase/16

    // writer byte offsets (r-waves; even lanes store packed u32 = cols j,j+1)
    const int wkk = j >> 5, wkg = (j >> 3) & 3;
    const u32 rest   = (u32)wkk * 1024u + (u32)wkg * 256u
                     + (u32)kg * 64u + ((u32)(n & 7) << 1);
    const u32 wbyteA = (u32)wg * 32768u + rest;
    const u32 wbyteB = (u32)mi * 131072u + (u32)(wg & 1) * 32768u + rest;

    // reader u64 offsets (full K, this wave's rows; same as R8)
    const u64* hbA = (const u64*)bufA + (size_t)wg * 4096 + lane * 2;
    const u64* hbB = (const u64*)bufB + (size_t)mi * 16384
                   + (size_t)(wg & 1) * 4096 + lane * 2;

    float hkeep[4] = {0.f, 0.f, 0.f, 0.f};      // r-waves: own h elements

    __syncthreads();

    for (int t = 0; t < SS; ++t) {
        f4v acc_a = {0.f,0.f,0.f,0.f};          // r/z: gi+gh chain; n: gi (acc_in)
        f4v acc_b = {0.f,0.f,0.f,0.f};          // n: gh chain (acc_hn)
        s8v areg[32];

        // ---- issue h_{t-1} LLC loads FIRST (full K) ----
        if (t > 0) {
            const u64* hb = (t & 1) ? hbA : hbB;
            #pragma unroll
            for (int kk = 0; kk < 32; ++kk) {
                u64 lo = __hip_atomic_load(hb + kk * 128,
                                           __ATOMIC_RELAXED, __HIP_MEMORY_SCOPE_AGENT);
                u64 hi = __hip_atomic_load(hb + kk * 128 + 1,
                                           __ATOMIC_RELAXED, __HIP_MEMORY_SCOPE_AGENT);
                union { u64 q[2]; s8v v; } u; u.q[0] = lo; u.q[1] = hi;
                areg[kk] = u.v;
            }
        }
        __builtin_amdgcn_sched_barrier(0);   // pin load issue before gi

        // ---- gi: X[:,t,:] @ Wih_gate^T (K=512), R8's kk order ----
        {
            const float* xrow = X + ((size_t)(rowbase + n) * SS + t) * IND;
            #pragma unroll 4
            for (int kk = 0; kk < IND / 32; ++kk) {
                const int k0 = kk * 32 + kg * 8;
                const float4* px = (const float4*)(xrow + k0);
                float4 x0 = px[0], x1 = px[1];
                s8v a;
                a[0]=f2bf(x0.x); a[1]=f2bf(x0.y); a[2]=f2bf(x0.z); a[3]=f2bf(x0.w);
                a[4]=f2bf(x1.x); a[5]=f2bf(x1.y); a[6]=f2bf(x1.z); a[7]=f2bf(x1.w);
                s8v bfrag = *(const s8v*)&wih_lds[(g * 16 + n) * WIH_LD + k0];
                acc_a = __builtin_amdgcn_mfma_f32_16x16x32_bf16(a, bfrag, acc_a, 0,0,0);
            }
        }

        // ---- gh: h_{t-1} @ Whh_gate^T (K=1024), R8's kk order ----
        if (t > 0) {
            if (g < 2) {        // r, z: continue the SAME chain (as R8)
                #pragma unroll
                for (int kk = 0; kk < 32; ++kk) {
                    const int k0 = kk * 32 + kg * 8;
                    s8v bfrag = *(const s8v*)&whh_lds[(g * 16 + n) * WHH_LD + k0];
                    acc_a = __builtin_amdgcn_mfma_f32_16x16x32_bf16(areg[kk], bfrag, acc_a, 0,0,0);
                }
            } else {            // n: separate hn chain (as R8's acc_hn)
                #pragma unroll
                for (int kk = 0; kk < 32; ++kk) {
                    const int k0 = kk * 32 + kg * 8;
                    s8v bfrag = *(const s8v*)&whh_lds[(2 * 16 + n) * WHH_LD + k0];
                    acc_b = __builtin_amdgcn_mfma_f32_16x16x32_bf16(areg[kk], bfrag, acc_b, 0,0,0);
                }
            }
        }

        // ---- gate exchange: z/n waves dump partials (bit-exact copies) ----
        if (g == 1) {
            red_lds[0][rw][lane] = acc_a;                      // acc_z
        } else if (g == 2) {
            red_lds[1][rw][lane] = acc_a;                      // acc_in
            red_lds[2][rw][lane] = acc_b;                      // acc_hn
        }
        __syncthreads();

        if (g == 0) {
            const f4v acc_r  = acc_a;
            const f4v acc_z  = red_lds[0][rw][lane];
            const f4v acc_in = red_lds[1][rw][lane];
            const f4v acc_hn = red_lds[2][rw][lane];

            // ---- R8 epilogue, verbatim op order ----
            u32 packv[4];
            #pragma unroll
            for (int r = 0; r < 4; ++r) {
                const int b = rowbase + kg * 4 + r;
                float gr = acc_r[r] + bir + bhr;
                float gz = acc_z[r] + biz + bhz;
                float rr = 1.f / (1.f + __expf(-gr));
                float zz = 1.f / (1.f + __expf(-gz));
                float hn = acc_hn[r] + bhn;                   // t=0: == bhn
                float na = acc_in[r] + bin_ + rr * hn;
                float e2 = __expf(2.f * na);
                float nn = (e2 - 1.f) / (e2 + 1.f);
                float hnew = (1.f - zz) * nn + zz * hkeep[r];
                hkeep[r] = hnew;
                out[(size_t)b * (SS * HID) + (size_t)t * HID + j] = hnew;
                if (t == SS - 1)
                    out[(size_t)BB * SS * HID + (size_t)b * HID + j] = hnew;
                u32 hb16  = (u32)(unsigned short)f2bf(hnew);
                u32 other = (u32)__shfl_xor((int)hb16, 1);
                packv[r] = hb16 | (other << 16);              // cols j (lo), j+1 (hi)
            }
            if (t < SS - 1 && !(n & 1)) {
                char* base = (t & 1) ? ((char*)bufB + wbyteB) : ((char*)bufA + wbyteA);
                #pragma unroll
                for (int r = 0; r < 4; ++r)
                    __hip_atomic_store((u32*)(base + r * 16), packv[r],
                                       __ATOMIC_RELAXED, __HIP_MEMORY_SCOPE_AGENT);
            }
        }

        if (t < SS - 1) {
            // ---- per-mi-group barrier (64 blocks), striped fan-in + poll.
            // __syncthreads: each wave drains its own vmcnt(0) before s_barrier,
            // so r-waves' h stores are at LLC before the leader's arrive.
            __syncthreads();
            if (tid == 0) {
                __hip_atomic_fetch_add(&ctr[(mi * NSTRIPE + (blk & 7)) * 8], 1ull,
                                       __ATOMIC_RELAXED, __HIP_MEMORY_SCOPE_AGENT);
                const u64 target = (u64)GRPBLK * (u64)(t + 1);
                for (;;) {
                    u64 s = 0;
                    #pragma unroll
                    for (int i = 0; i < NSTRIPE; ++i)
                        s += __hip_atomic_load(&ctr[(mi * NSTRIPE + i) * 8],
                                               __ATOMIC_RELAXED,
                                               __HIP_MEMORY_SCOPE_AGENT);
                    if (s >= target) break;
                    __builtin_amdgcn_s_sleep(1);
                }
            }
            __syncthreads();
        }
    }
}

extern "C" void kernel_launch(void* const* d_in, const int* in_sizes, int n_in,
                              void* d_out, int out_size, void* d_ws, size_t ws_size,
                              hipStream_t stream) {
    const float* X   = (const float*)d_in[0];
    const float* Wih = (const float*)d_in[1];
    const float* Whh = (const float*)d_in[2];
    const float* bih = (const float*)d_in[3];
    const float* bhh = (const float*)d_in[4];
    float* out = (float*)d_out;

    u64*   ctr  = (u64*)d_ws;                         // 4x8 stripes on 64B stride
    short* bufA = (short*)((char*)d_ws + 4096);       // 256 KB (even-t h)
    // odd-t h: per-group 64 KB slices inside each group's OWN h_last rows
    // (tail bytes [mi*128KB, +64KB)); overwritten group-locally at t=SS-1
    // after the group's t=SS-2 barrier.
    short* bufB = (short*)(out + (size_t)BB * SS * HID);

    hipMemsetAsync(d_ws, 0, 4096, stream);            // zero barrier stripes

    void* args[] = { (void*)&X, (void*)&Wih, (void*)&Whh, (void*)&bih,
                     (void*)&bhh, (void*)&out, (void*)&bufA, (void*)&bufB,
                     (void*)&ctr };
    hipLaunchCooperativeKernel((const void*)gru_persistent,
                               dim3(NBLK), dim3(NTHR), args, 0, stream);
}

// Round 11
// 5474.762 us; speedup vs baseline: 1.3568x; 1.3568x over previous
//
#include <hip/hip_runtime.h>
#include <hip/hip_bf16.h>

// Problem constants
#define BB   128
#define SS   512
#define IND  512
#define HID  1024
#define NBLK 256     // 4 row-quarters (mi) x 64 column-groups (jg)
#define GRPBLK 64    // blocks per mi-group (independent sub-GRU)
#define NSTRIPE 8    // stripes per group (one 64B LLC line each)
#define NTHR 256     // 4 waves: 0,1 = consumers (gh+gates), 2,3 = producers (gi)

#define WHH_LD (HID + 8)   // LDS row pad
#define WIH_LD (IND + 8)

typedef __attribute__((ext_vector_type(8))) short s8v;   // 8 x bf16
typedef __attribute__((ext_vector_type(4))) float f4v;   // MFMA accumulator
typedef unsigned long long u64;
typedef unsigned int u32;

__device__ __forceinline__ short f2bf(float f) {
    union { float f; u32 u; } v; v.f = f;
    u32 u = v.u + 0x7FFFu + ((v.u >> 16) & 1u);          // RNE
    return (short)(u >> 16);
}

// h ping-pong layout (bf16): as R8 (PROVEN).
//   bufA (ws): [wg=8][kk=32][kg=4][row 16][8 shorts]
//   bufB (out tail): group mi slice at mi*131072 + (wg&1)*32768 + rest
// Producer waves compute gi[t+1] (R8's exact MFMA chain) into gibuf
// (LDS f32, exact round-trip); consumer waves initialize acc from gibuf and
// continue the gh chain -> h evolution bit-identical to R8.

__global__ void __launch_bounds__(NTHR, 1)
gru_persistent(const float* __restrict__ X,     // [B,S,IND]
               const float* __restrict__ Wih,   // [3H, IND]
               const float* __restrict__ Whh,   // [3H, HID]
               const float* __restrict__ bih,   // [3H]
               const float* __restrict__ bhh,   // [3H]
               float* __restrict__ out,         // [B,S,H] ++ [B,H]
               short* __restrict__ bufA,        // ws scratch (even t)
               short* __restrict__ bufB,        // d_out tail region (odd t)
               u64*   __restrict__ ctr)         // 4 groups x 8 stripes, 64B apart
{
    __shared__ __align__(16) short whh_lds[48 * WHH_LD];   //  99072 B
    __shared__ __align__(16) short wih_lds[48 * WIH_LD];   //  49920 B
    __shared__ __align__(16) f4v  gibuf[2][3][2][64];      //  12288 B (parity, gate, rw, lane)

    const int tid  = threadIdx.x;
    const int wave = tid >> 6;      // 0..3
    const int lane = tid & 63;
    const int blk  = blockIdx.x;
    const int mi   = blk >> 6;      // 0..3 row quarter == barrier group
    const int jg   = blk & 63;      // column group

    const int consumer = (wave < 2);
    const int rw = wave & 1;        // row half (for both roles)

    // ---- stage weight slices to LDS as bf16 (once) ----
    for (int idx = tid; idx < 48 * (HID / 4); idx += NTHR) {
        int s = idx / (HID / 4), k4 = idx % (HID / 4);
        int grow = (s >> 4) * HID + jg * 16 + (s & 15);
        float4 v = *(const float4*)(Whh + (size_t)grow * HID + k4 * 4);
        short* d = &whh_lds[s * WHH_LD + k4 * 4];
        d[0] = f2bf(v.x); d[1] = f2bf(v.y); d[2] = f2bf(v.z); d[3] = f2bf(v.w);
    }
    for (int idx = tid; idx < 48 * (IND / 4); idx += NTHR) {
        int s = idx / (IND / 4), k4 = idx % (IND / 4);
        int grow = (s >> 4) * HID + jg * 16 + (s & 15);
        float4 v = *(const float4*)(Wih + (size_t)grow * IND + k4 * 4);
        short* d = &wih_lds[s * WIH_LD + k4 * 4];
        d[0] = f2bf(v.x); d[1] = f2bf(v.y); d[2] = f2bf(v.z); d[3] = f2bf(v.w);
    }

    const int n  = lane & 15;
    const int kg = lane >> 4;
    const int j  = jg * 16 + n;
    const float bir = bih[j], biz = bih[HID + j], bin_ = bih[2 * HID + j];
    const float bhr = bhh[j], bhz = bhh[HID + j], bhn  = bhh[2 * HID + j];

    const int rowbase = mi * 32 + rw * 16;
    const int wg      = mi * 2 + rw;            // row-group = rowbase/16

    // writer byte offsets (consumers; even lanes store packed u32 = cols j,j+1)
    const int wkk = j >> 5, wkg = (j >> 3) & 3;
    const u32 rest   = (u32)wkk * 1024u + (u32)wkg * 256u
                     + (u32)kg * 64u + ((u32)(n & 7) << 1);
    const u32 wbyteA = (u32)wg * 32768u + rest;
    const u32 wbyteB = (u32)mi * 131072u + (u32)(wg & 1) * 32768u + rest;

    // reader u64 offsets (full K, this wave's rows; same as R8)
    const u64* hbA = (const u64*)bufA + (size_t)wg * 4096 + lane * 2;
    const u64* hbB = (const u64*)bufB + (size_t)mi * 16384
                   + (size_t)(wg & 1) * 4096 + lane * 2;

    float hkeep[4] = {0.f, 0.f, 0.f, 0.f};      // consumers: own h elements

    __syncthreads();

    // ---- prologue: producers fill gi[0] into gibuf[0] ----
    if (!consumer) {
        f4v gr = {0.f,0.f,0.f,0.f}, gz = gr, gn = gr;
        const float* xrow = X + ((size_t)(rowbase + n) * SS + 0) * IND;
        #pragma unroll 4
        for (int kk = 0; kk < IND / 32; ++kk) {
            const int k0 = kk * 32 + kg * 8;
            const float4* px = (const float4*)(xrow + k0);
            float4 x0 = px[0], x1 = px[1];
            s8v a;
            a[0]=f2bf(x0.x); a[1]=f2bf(x0.y); a[2]=f2bf(x0.z); a[3]=f2bf(x0.w);
            a[4]=f2bf(x1.x); a[5]=f2bf(x1.y); a[6]=f2bf(x1.z); a[7]=f2bf(x1.w);
            s8v br = *(const s8v*)&wih_lds[(0 * 16 + n) * WIH_LD + k0];
            s8v bz = *(const s8v*)&wih_lds[(1 * 16 + n) * WIH_LD + k0];
            s8v bn = *(const s8v*)&wih_lds[(2 * 16 + n) * WIH_LD + k0];
            gr = __builtin_amdgcn_mfma_f32_16x16x32_bf16(a, br, gr, 0,0,0);
            gz = __builtin_amdgcn_mfma_f32_16x16x32_bf16(a, bz, gz, 0,0,0);
            gn = __builtin_amdgcn_mfma_f32_16x16x32_bf16(a, bn, gn, 0,0,0);
        }
        gibuf[0][0][rw][lane] = gr;
        gibuf[0][1][rw][lane] = gz;
        gibuf[0][2][rw][lane] = gn;
    }
    __syncthreads();

    for (int t = 0; t < SS; ++t) {
        if (consumer) {
            s8v areg[32];
            if (t > 0) {
                const u64* hb = (t & 1) ? hbA : hbB;
                #pragma unroll
                for (int kk = 0; kk < 32; ++kk) {
                    u64 lo = __hip_atomic_load(hb + kk * 128,
                                               __ATOMIC_RELAXED, __HIP_MEMORY_SCOPE_AGENT);
                    u64 hi = __hip_atomic_load(hb + kk * 128 + 1,
                                               __ATOMIC_RELAXED, __HIP_MEMORY_SCOPE_AGENT);
                    union { u64 q[2]; s8v v; } u; u.q[0] = lo; u.q[1] = hi;
                    areg[kk] = u.v;
                }
            }
            // acc init = gi (f32 exact round-trip through LDS)
            f4v acc_r  = gibuf[t & 1][0][rw][lane];
            f4v acc_z  = gibuf[t & 1][1][rw][lane];
            f4v acc_in = gibuf[t & 1][2][rw][lane];
            f4v acc_hn = {0.f,0.f,0.f,0.f};

            // ---- gh: h_{t-1} @ Whh_slice^T (K=1024), R8's chain continued ----
            if (t > 0) {
                #pragma unroll
                for (int kk = 0; kk < 32; ++kk) {
                    const int k0 = kk * 32 + kg * 8;
                    s8v br = *(const s8v*)&whh_lds[(0 * 16 + n) * WHH_LD + k0];
                    s8v bz = *(const s8v*)&whh_lds[(1 * 16 + n) * WHH_LD + k0];
                    s8v bn = *(const s8v*)&whh_lds[(2 * 16 + n) * WHH_LD + k0];
                    acc_r  = __builtin_amdgcn_mfma_f32_16x16x32_bf16(areg[kk], br, acc_r,  0,0,0);
                    acc_z  = __builtin_amdgcn_mfma_f32_16x16x32_bf16(areg[kk], bz, acc_z,  0,0,0);
                    acc_hn = __builtin_amdgcn_mfma_f32_16x16x32_bf16(areg[kk], bn, acc_hn, 0,0,0);
                }
            }

            // ---- gates + state update (R8 epilogue verbatim) ----
            u32 packv[4];
            #pragma unroll
            for (int r = 0; r < 4; ++r) {
                const int b = rowbase + kg * 4 + r;
                float gr = acc_r[r] + bir + bhr;
                float gz = acc_z[r] + biz + bhz;
                float rr = 1.f / (1.f + __expf(-gr));
                float zz = 1.f / (1.f + __expf(-gz));
                float hn = acc_hn[r] + bhn;                   // t=0: == bhn
                float na = acc_in[r] + bin_ + rr * hn;
                float e2 = __expf(2.f * na);
                float nn = (e2 - 1.f) / (e2 + 1.f);
                float hnew = (1.f - zz) * nn + zz * hkeep[r];
                hkeep[r] = hnew;
                out[(size_t)b * (SS * HID) + (size_t)t * HID + j] = hnew;
                if (t == SS - 1)
                    out[(size_t)BB * SS * HID + (size_t)b * HID + j] = hnew;
                u32 hb16  = (u32)(unsigned short)f2bf(hnew);
                u32 other = (u32)__shfl_xor((int)hb16, 1);
                packv[r] = hb16 | (other << 16);              // cols j (lo), j+1 (hi)
            }
            if (t < SS - 1 && !(n & 1)) {
                char* base = (t & 1) ? ((char*)bufB + wbyteB) : ((char*)bufA + wbyteA);
                #pragma unroll
                for (int r = 0; r < 4; ++r)
                    __hip_atomic_store((u32*)(base + r * 16), packv[r],
                                       __ATOMIC_RELAXED, __HIP_MEMORY_SCOPE_AGENT);
            }
        } else if (t < SS - 1) {
            // ---- producers: gi[t+1] into gibuf[(t+1)&1] (R8's exact chain) ----
            f4v gr = {0.f,0.f,0.f,0.f}, gz = gr, gn = gr;
            const float* xrow = X + ((size_t)(rowbase + n) * SS + (t + 1)) * IND;
            #pragma unroll 4
            for (int kk = 0; kk < IND / 32; ++kk) {
                const int k0 = kk * 32 + kg * 8;
                const float4* px = (const float4*)(xrow + k0);
                float4 x0 = px[0], x1 = px[1];
                s8v a;
                a[0]=f2bf(x0.x); a[1]=f2bf(x0.y); a[2]=f2bf(x0.z); a[3]=f2bf(x0.w);
                a[4]=f2bf(x1.x); a[5]=f2bf(x1.y); a[6]=f2bf(x1.z); a[7]=f2bf(x1.w);
                s8v br = *(const s8v*)&wih_lds[(0 * 16 + n) * WIH_LD + k0];
                s8v bz = *(const s8v*)&wih_lds[(1 * 16 + n) * WIH_LD + k0];
                s8v bn = *(const s8v*)&wih_lds[(2 * 16 + n) * WIH_LD + k0];
                gr = __builtin_amdgcn_mfma_f32_16x16x32_bf16(a, br, gr, 0,0,0);
                gz = __builtin_amdgcn_mfma_f32_16x16x32_bf16(a, bz, gz, 0,0,0);
                gn = __builtin_amdgcn_mfma_f32_16x16x32_bf16(a, bn, gn, 0,0,0);
            }
            gibuf[(t + 1) & 1][0][rw][lane] = gr;
            gibuf[(t + 1) & 1][1][rw][lane] = gz;
            gibuf[(t + 1) & 1][2][rw][lane] = gn;
        }

        if (t < SS - 1) {
            // ---- per-mi-group barrier (64 blocks), striped fan-in + poll.
            // __syncthreads: each wave drains its own vmcnt(0)/lgkmcnt before
            // s_barrier, so consumers' h stores are at LLC and producers' gi
            // writes are in LDS before anyone proceeds.
            __syncthreads();
            if (tid == 0) {
                __hip_atomic_fetch_add(&ctr[(mi * NSTRIPE + (blk & 7)) * 8], 1ull,
                                       __ATOMIC_RELAXED, __HIP_MEMORY_SCOPE_AGENT);
                const u64 target = (u64)GRPBLK * (u64)(t + 1);
                for (;;) {
                    u64 s = 0;
                    #pragma unroll
                    for (int i = 0; i < NSTRIPE; ++i)
                        s += __hip_atomic_load(&ctr[(mi * NSTRIPE + i) * 8],
                                               __ATOMIC_RELAXED,
                                               __HIP_MEMORY_SCOPE_AGENT);
                    if (s >= target) break;
                    __builtin_amdgcn_s_sleep(1);
                }
            }
            __syncthreads();
        }
    }
}

extern "C" void kernel_launch(void* const* d_in, const int* in_sizes, int n_in,
                              void* d_out, int out_size, void* d_ws, size_t ws_size,
                              hipStream_t stream) {
    const float* X   = (const float*)d_in[0];
    const float* Wih = (const float*)d_in[1];
    const float* Whh = (const float*)d_in[2];
    const float* bih = (const float*)d_in[3];
    const float* bhh = (const float*)d_in[4];
    float* out = (float*)d_out;

    u64*   ctr  = (u64*)d_ws;                         // 4x8 stripes on 64B stride
    short* bufA = (short*)((char*)d_ws + 4096);       // 256 KB (even-t h)
    // odd-t h: per-group 64 KB slices inside each group's OWN h_last rows
    // (tail bytes [mi*128KB, +64KB)); overwritten group-locally at t=SS-1
    // after the group's t=SS-2 barrier.
    short* bufB = (short*)(out + (size_t)BB * SS * HID);

    hipMemsetAsync(d_ws, 0, 4096, stream);            // zero barrier stripes

    void* args[] = { (void*)&X, (void*)&Wih, (void*)&Whh, (void*)&bih,
                     (void*)&bhh, (void*)&out, (void*)&bufA, (void*)&bufB,
                     (void*)&ctr };
    hipLaunchCooperativeKernel((const void*)gru_persistent,
                               dim3(NBLK), dim3(NTHR), args, 0, stream);
}